// Round 18
// baseline (239.923 us; speedup 1.0000x reference)
//
#include <hip/hip_runtime.h>
#include <cstdint>
#include <cstddef>

#define GN 16384          // nodes
#define GF 64             // features
#define NW (GN / 32)      // 512 words per column (logical)

typedef __bf16 bf16x8 __attribute__((ext_vector_type(8)));
typedef float f32x4 __attribute__((ext_vector_type(4)));
typedef unsigned int u32x4 __attribute__((ext_vector_type(4)));

// R2/R6/R7-validated cheap decode.
__device__ __forceinline__ bf16x8 decode8(unsigned int b) {
  unsigned int t = (b & 0xffu) * 0x8001u;
  u32x4 r;
  r[0] = (t & 0x00010001u) * 0x3F80u;
  r[1] = ((t >> 2) & 0x00010001u) * 0x3F80u;
  r[2] = ((t >> 4) & 0x00010001u) * 0x3F80u;
  r[3] = ((t >> 6) & 0x00010001u) * 0x3F80u;
  return __builtin_bit_cast(bf16x8, r);
}

__device__ __forceinline__ unsigned short f2bf(float v) {  // RNE f32->bf16
  unsigned int u = __builtin_bit_cast(unsigned int, v);
  u += 0x7fffu + ((u >> 16) & 1u);
  return (unsigned short)(u >> 16);
}

__device__ __forceinline__ float bf2f(unsigned short s) {
  return __builtin_bit_cast(float, (unsigned int)s << 16);
}

// ---------------------------------------------------------------------------
// K1 v8: LONG-BURST READS. Block = 4096 cols x 128 rows (grid 512 = 4 cb x
// 128 jb; same 2 blocks/CU as R17). Per row the block reads 16 KB contiguous
// (4 wave-loads of 4 KB) instead of 4 KB -> 4x longer DRAM bursts. Store
// layout bit-identical to R17 quad-major: packed[(jb*GN + col)*4 + q].
// deg via u8 partial counts (no atomics; counts <= 128 fit u8; exact ints).
// ---------------------------------------------------------------------------
__global__ __launch_bounds__(256) void k_pack(const float* __restrict__ adj,
                                              unsigned char* __restrict__ cnt8,
                                              unsigned int* __restrict__ packed) {
  const int cb = blockIdx.x >> 7;      // 0..3   (4096-column slice)
  const int jb = blockIdx.x & 127;     // 0..127 (128-row slab = quad index)
  const int col0 = cb * 4096 + (int)threadIdx.x * 4;
  const int j0 = jb * 128;

  u32x4 wq[4][4];  // [cc][j] -> 4 words (q=0..3) for col col0+cc*1024+j
#pragma unroll
  for (int cc = 0; cc < 4; ++cc)
#pragma unroll
    for (int j = 0; j < 4; ++j) wq[cc][j] = (u32x4){0u, 0u, 0u, 0u};

#pragma unroll
  for (int q = 0; q < 4; ++q) {        // 32 rows per word
    unsigned int w[4][4];
#pragma unroll
    for (int cc = 0; cc < 4; ++cc)
#pragma unroll
      for (int j = 0; j < 4; ++j) w[cc][j] = 0u;
#pragma unroll 4
    for (int b = 0; b < 32; ++b) {
      const float* rowp = adj + (size_t)(j0 + q * 32 + b) * GN + col0;
      const unsigned int m = 1u << b;
#pragma unroll
      for (int cc = 0; cc < 4; ++cc) {
        f32x4 a = *(const f32x4*)(rowp + cc * 1024);
        if (a.x != 0.f) w[cc][0] |= m;
        if (a.y != 0.f) w[cc][1] |= m;
        if (a.z != 0.f) w[cc][2] |= m;
        if (a.w != 0.f) w[cc][3] |= m;
      }
    }
#pragma unroll
    for (int cc = 0; cc < 4; ++cc)
#pragma unroll
      for (int j = 0; j < 4; ++j) wq[cc][j][q] = w[cc][j];
  }

  // quad-major stores: per cc a 4 KB-contiguous wave store (64 KB per block)
#pragma unroll
  for (int cc = 0; cc < 4; ++cc) {
    unsigned int* q0 = packed + ((size_t)jb * GN + col0 + cc * 1024) * 4;
    *(u32x4*)(q0 + 0)  = wq[cc][0];
    *(u32x4*)(q0 + 4)  = wq[cc][1];
    *(u32x4*)(q0 + 8)  = wq[cc][2];
    *(u32x4*)(q0 + 12) = wq[cc][3];
  }

  // u8 partial counts, 4 cols per dword store, no atomics
#pragma unroll
  for (int cc = 0; cc < 4; ++cc) {
    unsigned int c0 = __popc(wq[cc][0][0]) + __popc(wq[cc][0][1]) +
                      __popc(wq[cc][0][2]) + __popc(wq[cc][0][3]);
    unsigned int c1 = __popc(wq[cc][1][0]) + __popc(wq[cc][1][1]) +
                      __popc(wq[cc][1][2]) + __popc(wq[cc][1][3]);
    unsigned int c2 = __popc(wq[cc][2][0]) + __popc(wq[cc][2][1]) +
                      __popc(wq[cc][2][2]) + __popc(wq[cc][2][3]);
    unsigned int c3 = __popc(wq[cc][3][0]) + __popc(wq[cc][3][1]) +
                      __popc(wq[cc][3][2]) + __popc(wq[cc][3][3]);
    *(unsigned int*)(cnt8 + (size_t)jb * GN + col0 + cc * 1024) =
        c0 | (c1 << 8) | (c2 << 16) | (c3 << 24);
  }
}

// ---------------------------------------------------------------------------
// K2 v5: deg from 128 u8 partials (exact ints -> bit-identical dinv).
// Otherwise identical to R16/R17 (lane-linear z2).
// ---------------------------------------------------------------------------
__global__ __launch_bounds__(256) void k_z(const float* __restrict__ x,
                                           const float* __restrict__ W,
                                           const unsigned char* __restrict__ cnt8,
                                           float* __restrict__ dinv,
                                           unsigned short* __restrict__ z_rm,
                                           unsigned short* __restrict__ z2) {
  __shared__ float Wl[64][64];
  __shared__ float xl[64][64];
  __shared__ float degl[64];  // deg + 1 (self-loop)
  const int tid = threadIdx.x;
  const int f = tid & 63;
  const int w = tid >> 6;
  const int rowB = blockIdx.x * 64;

  for (int idx = tid; idx < 4096; idx += 256) {
    Wl[idx >> 6][idx & 63] = W[idx];
    xl[idx >> 6][idx & 63] = x[(size_t)rowB * 64 + idx];
  }
  if (tid < 64) {
    int s = 1;  // self-loop
    for (int jbb = 0; jbb < 128; ++jbb)
      s += (int)cnt8[(size_t)jbb * GN + rowB + tid];
    degl[tid] = (float)s;
  }
  __syncthreads();

  float acc[16];
#pragma unroll
  for (int r = 0; r < 16; ++r) acc[r] = 0.f;
  for (int k = 0; k < 64; ++k) {
    float wk = Wl[k][f];
#pragma unroll
    for (int r = 0; r < 16; ++r) acc[r] = fmaf(xl[w * 16 + r][k], wk, acc[r]);
  }

  const int row0 = rowB + w * 16;
  if (f < 16) {
    int row = row0 + f;
    dinv[row] = 1.0f / sqrtf(degl[w * 16 + f]);
  }

  unsigned short zs[16];
#pragma unroll
  for (int r = 0; r < 16; ++r) {
    float di = 1.0f / sqrtf(degl[w * 16 + r]);
    unsigned short zb = f2bf(di * acc[r]);
    zs[r] = zb;
    z_rm[(size_t)(row0 + r) * GF + f] = zb;
  }
  unsigned int p[8];
#pragma unroll
  for (int i = 0; i < 8; ++i)
    p[i] = (unsigned int)zs[2 * i] | ((unsigned int)zs[2 * i + 1] << 16);
  // lane-linear layout (R16): kb = 2*(w&1) + (r>>3), e = r&7
  char* dst = (char*)z2 + (size_t)((rowB >> 5) + (w >> 1)) * 4096 +
              (f >> 4) * 1024 + ((2 * (w & 1)) * 16 + (f & 15)) * 16;
  u32x4 lo = {p[0], p[1], p[2], p[3]};
  u32x4 hi = {p[4], p[5], p[6], p[7]};
  *(u32x4*)dst = lo;
  *(u32x4*)(dst + 256) = hi;
}

// ---------------------------------------------------------------------------
// K3 (byte-identical to R17 v13): setprio + lane-linear z2 + quad-major bits.
// ---------------------------------------------------------------------------
__global__ __launch_bounds__(512) void k_spmm(const unsigned int* __restrict__ packed,
                                              const unsigned short* __restrict__ z2,
                                              const unsigned short* __restrict__ z_rm,
                                              const float* __restrict__ dinv,
                                              const float* __restrict__ bias,
                                              float* __restrict__ out) {
  __shared__ float red[4][64][64];  // 64 KB
  const int i0 = blockIdx.x * 64;
  const int tid = threadIdx.x;
  const int wid = tid >> 6, lane = tid & 63;
  const int lrow = lane & 15, kb = lane >> 4;
  const int sh = kb * 8;

  f32x4 acc[4][4];
#pragma unroll
  for (int m = 0; m < 4; ++m)
#pragma unroll
    for (int n = 0; n < 4; ++n) acc[m][n] = (f32x4){0.f, 0.f, 0.f, 0.f};

  const size_t qstep = (size_t)GN * 4;  // dwords per quad-row
  const unsigned int* pr0 = packed + (size_t)(wid * 16) * qstep / 4 * 4 +
                            (size_t)(i0 + 0 * 16 + lrow) * 4;
  const unsigned int* pr1 = packed + (size_t)(wid * 16) * qstep / 4 * 4 +
                            (size_t)(i0 + 1 * 16 + lrow) * 4;
  const unsigned int* pr2 = packed + (size_t)(wid * 16) * qstep / 4 * 4 +
                            (size_t)(i0 + 2 * 16 + lrow) * 4;
  const unsigned int* pr3 = packed + (size_t)(wid * 16) * qstep / 4 * 4 +
                            (size_t)(i0 + 3 * 16 + lrow) * 4;
  const char* zbase = (const char*)z2 + (size_t)(wid * 64) * 4096 + lane * 16;

  bf16x8 cur0 = *(const bf16x8*)(zbase + 0 * 1024);
  bf16x8 cur1 = *(const bf16x8*)(zbase + 1 * 1024);
  bf16x8 cur2 = *(const bf16x8*)(zbase + 2 * 1024);
  bf16x8 cur3 = *(const bf16x8*)(zbase + 3 * 1024);
  u32x4 bits0 = *(const u32x4*)pr0;
  u32x4 bits1 = *(const u32x4*)pr1;
  u32x4 bits2 = *(const u32x4*)pr2;
  u32x4 bits3 = *(const u32x4*)pr3;

  for (int it = 0; it < 16; ++it) {
    u32x4 nb0 = *(const u32x4*)(pr0 + qstep);
    u32x4 nb1 = *(const u32x4*)(pr1 + qstep);
    u32x4 nb2 = *(const u32x4*)(pr2 + qstep);
    u32x4 nb3 = *(const u32x4*)(pr3 + qstep);
#pragma unroll
    for (int s = 0; s < 4; ++s) {
      const char* zn = zbase + (s + 1) * 4096;
      bf16x8 n0 = *(const bf16x8*)(zn + 0 * 1024);
      bf16x8 n1 = *(const bf16x8*)(zn + 1 * 1024);
      bf16x8 n2 = *(const bf16x8*)(zn + 2 * 1024);
      bf16x8 n3 = *(const bf16x8*)(zn + 3 * 1024);

      __builtin_amdgcn_s_setprio(1);
      bf16x8 a0 = decode8(bits0[s] >> sh);
      acc[0][0] = __builtin_amdgcn_mfma_f32_16x16x32_bf16(a0, cur0, acc[0][0], 0, 0, 0);
      acc[0][1] = __builtin_amdgcn_mfma_f32_16x16x32_bf16(a0, cur1, acc[0][1], 0, 0, 0);
      acc[0][2] = __builtin_amdgcn_mfma_f32_16x16x32_bf16(a0, cur2, acc[0][2], 0, 0, 0);
      acc[0][3] = __builtin_amdgcn_mfma_f32_16x16x32_bf16(a0, cur3, acc[0][3], 0, 0, 0);
      bf16x8 a1 = decode8(bits1[s] >> sh);
      acc[1][0] = __builtin_amdgcn_mfma_f32_16x16x32_bf16(a1, cur0, acc[1][0], 0, 0, 0);
      acc[1][1] = __builtin_amdgcn_mfma_f32_16x16x32_bf16(a1, cur1, acc[1][1], 0, 0, 0);
      acc[1][2] = __builtin_amdgcn_mfma_f32_16x16x32_bf16(a1, cur2, acc[1][2], 0, 0, 0);
      acc[1][3] = __builtin_amdgcn_mfma_f32_16x16x32_bf16(a1, cur3, acc[1][3], 0, 0, 0);
      bf16x8 a2 = decode8(bits2[s] >> sh);
      acc[2][0] = __builtin_amdgcn_mfma_f32_16x16x32_bf16(a2, cur0, acc[2][0], 0, 0, 0);
      acc[2][1] = __builtin_amdgcn_mfma_f32_16x16x32_bf16(a2, cur1, acc[2][1], 0, 0, 0);
      acc[2][2] = __builtin_amdgcn_mfma_f32_16x16x32_bf16(a2, cur2, acc[2][2], 0, 0, 0);
      acc[2][3] = __builtin_amdgcn_mfma_f32_16x16x32_bf16(a2, cur3, acc[2][3], 0, 0, 0);
      bf16x8 a3 = decode8(bits3[s] >> sh);
      acc[3][0] = __builtin_amdgcn_mfma_f32_16x16x32_bf16(a3, cur0, acc[3][0], 0, 0, 0);
      acc[3][1] = __builtin_amdgcn_mfma_f32_16x16x32_bf16(a3, cur1, acc[3][1], 0, 0, 0);
      acc[3][2] = __builtin_amdgcn_mfma_f32_16x16x32_bf16(a3, cur2, acc[3][2], 0, 0, 0);
      acc[3][3] = __builtin_amdgcn_mfma_f32_16x16x32_bf16(a3, cur3, acc[3][3], 0, 0, 0);
      __builtin_amdgcn_s_setprio(0);

      cur0 = n0; cur1 = n1; cur2 = n2; cur3 = n3;
    }
    bits0 = nb0; bits1 = nb1; bits2 = nb2; bits3 = nb3;
    pr0 += qstep; pr1 += qstep; pr2 += qstep; pr3 += qstep;
    zbase += 16384;
  }

  if (wid < 4) {
#pragma unroll
    for (int m = 0; m < 4; ++m)
#pragma unroll
      for (int n = 0; n < 4; ++n)
#pragma unroll
        for (int r = 0; r < 4; ++r)
          red[wid][m * 16 + kb * 4 + r][n * 16 + lrow] = acc[m][n][r];
  }
  __syncthreads();
  if (wid >= 4) {
#pragma unroll
    for (int m = 0; m < 4; ++m)
#pragma unroll
      for (int n = 0; n < 4; ++n)
#pragma unroll
        for (int r = 0; r < 4; ++r)
          red[wid - 4][m * 16 + kb * 4 + r][n * 16 + lrow] += acc[m][n][r];
  }
  __syncthreads();

  const int c = tid & 63;
  const int rg = tid >> 6;
  const float bc = bias[c];
#pragma unroll
  for (int rr = 0; rr < 8; ++rr) {
    int r = rg * 8 + rr;
    int i = i0 + r;
    float s = red[0][r][c] + red[1][r][c] + red[2][r][c] + red[3][r][c];
    float o = dinv[i] * (s + bf2f(z_rm[(size_t)i * GF + c])) + bc;
    out[(size_t)i * GF + c] = fmaxf(o, 0.f);
  }
}

// ---------------------------------------------------------------------------
extern "C" void kernel_launch(void* const* d_in, const int* in_sizes, int n_in,
                              void* d_out, int out_size, void* d_ws, size_t ws_size,
                              hipStream_t stream) {
  const float* x = (const float*)d_in[0];
  const float* adj = (const float*)d_in[1];
  const float* W = (const float*)d_in[2];
  const float* bias = (const float*)d_in[3];
  float* out = (float*)d_out;

  char* ws = (char*)d_ws;
  unsigned char* cnt8 = (unsigned char*)ws;                       // 2 MB [128][16384] u8
  float* dinv = (float*)(ws + 2097152);                           // 64 KB
  unsigned short* z_rm = (unsigned short*)(ws + 2097152 + 65536); // 2 MB
  unsigned short* z2 = (unsigned short*)(ws + 4194304 + 65536);   // 2 MB lane-linear
  unsigned int* packed = (unsigned int*)(ws + 6291456 + 65536);   // 32 MB quad-major
  // need: 2M + 64K + 2M + 2M + 32M + 512K slack = 40,435,712 B  (R8 proved >= 42 MB)
  if (ws_size < 40435712u) return;

  k_pack<<<dim3(512), dim3(256), 0, stream>>>(adj, cnt8, packed);
  k_z<<<dim3(GN / 64), dim3(256), 0, stream>>>(x, W, cnt8, dinv, z_rm, z2);
  k_spmm<<<dim3(GN / 64), dim3(512), 0, stream>>>(packed, z2, z_rm, dinv, bias, out);
}